// Round 5
// baseline (496.766 us; speedup 1.0000x reference)
//
#include <hip/hip_runtime.h>

// ResidualVQ: Q=4, N_EMBED=1024, DIM=256, B=8, S=2048 (fp32).
// out = [quantized 8*2048*256][indices-as-float 4*8*2048][losses 4]
//
// R17: keep TM=32 (R14's win: 2 MFMAs per B-load, half the B traffic) but
// kill the cross-barrier acc liveness that drove R14/R15's 87-118MB scratch:
//  - gather PRE-barrier with per-wave threshold thr_w = wave_min + tau
//    (superset of certified set since global_min <= wave_min), storing the
//    fp32 d~ next to each code; acc dies before any barrier.
//  - post-barrier prune with the TRUE thrS = bd + tau: np_dist runs on
//    exactly R14's certified set (same fp32 values, same predicate) ->
//    outputs bit-identical. Overflow (cnt>CAP) -> exact fallback, unchanged.
//  - dispatch consolidation (every round showed ~85-105us of non-k_fused
//    time): k_cb16+k_b fused into k_prep; bmaxI eliminated (per-wave fp32
//    max over staged sBK == old atomicMax value bit-exactly); k_loss folded
//    into k_fused tail via device-scope done-counter. 2 dispatches total.
// Certified exact re-rank structure FROZEN (R11-R16): bf16-MFMA prefilter,
// tau margin 8x slack, frozen np fp32 distance chain, tie -> lower index,
// frozen STE recursion.
#define QQ   4
#define NE   1024
#define DIMD 256
#define MM   16384
#define TM   32
#define NW   8      // waves per block (512 threads)
#define CAP  32     // candidate slots per row

typedef short v8s __attribute__((ext_vector_type(8)));   // 8 x bf16
typedef float v4f __attribute__((ext_vector_type(4)));

// ws layout (float offsets):
//  cb16  [QQ][NE][DIMD] ushort @ 0        (524,288 floats)
//  bK    [QQ][NE]              @ 524,288  (4,096)
//  lossP double[QQ][64]        @ 528,384  (byte 2,113,536 %8==0; 512 floats)
//  done  uint                  @ 528,896

__device__ __forceinline__ unsigned short f2bf(float f) {  // RNE fp32->bf16
  unsigned u = __float_as_uint(f);
  return (unsigned short)((u + 0x7FFFu + ((u >> 16) & 1u)) >> 16);
}

// FROZEN numpy pairwise sumsq of 256 f32, over a 32-aligned group of 32 lanes
// (j = lane-in-group). Valid on j==0. Identical op tree/pairing as scalar.
__device__ __forceinline__ float np_sumsq_256_x32(const float* __restrict__ p,
                                                  int j) {
  const int bi = j >> 4, L = j & 15;
  const float* q = p + bi * 128 + L;
  float s0 = __fmul_rn(q[0], q[0]);
  float s1 = __fmul_rn(q[16], q[16]);
  float s2 = __fmul_rn(q[32], q[32]);
  float s3 = __fmul_rn(q[48], q[48]);
  float s4 = __fmul_rn(q[64], q[64]);
  float s5 = __fmul_rn(q[80], q[80]);
  float s6 = __fmul_rn(q[96], q[96]);
  float s7 = __fmul_rn(q[112], q[112]);
  float w = __fadd_rn(__fadd_rn(__fadd_rn(s0, s1), __fadd_rn(s2, s3)),
                      __fadd_rn(__fadd_rn(s4, s5), __fadd_rn(s6, s7)));
  float u  = __fadd_rn(w,  __shfl_down(w, 8, 64));   // valid L<8
  float t  = __fadd_rn(u,  __shfl_down(u, 4, 64));   // valid L<4
  float r2 = __fadd_rn(t,  __shfl_down(t, 2, 64));   // valid L<2
  float bb = __fadd_rn(r2, __shfl_down(r2, 1, 64));  // valid L==0 -> blk[bi]
  return __fadd_rn(bb, __shfl_down(bb, 16, 64));     // valid j==0
}

// Same frozen tree over 16 lanes (j=0..15 in a 16-aligned group); bi serial.
// Operand pairing of every __fadd_rn identical to the scalar chain -> bit-exact.
__device__ __forceinline__ float np_sumsq_256_x16(const float* __restrict__ p,
                                                  int j) {
  float blk[2];
  #pragma unroll
  for (int bi = 0; bi < 2; ++bi) {
    const float* q = p + bi * 128 + j;
    float s0 = __fmul_rn(q[0], q[0]);
    float s1 = __fmul_rn(q[16], q[16]);
    float s2 = __fmul_rn(q[32], q[32]);
    float s3 = __fmul_rn(q[48], q[48]);
    float s4 = __fmul_rn(q[64], q[64]);
    float s5 = __fmul_rn(q[80], q[80]);
    float s6 = __fmul_rn(q[96], q[96]);
    float s7 = __fmul_rn(q[112], q[112]);
    float w = __fadd_rn(__fadd_rn(__fadd_rn(s0, s1), __fadd_rn(s2, s3)),
                        __fadd_rn(__fadd_rn(s4, s5), __fadd_rn(s6, s7)));
    float u  = __fadd_rn(w,  __shfl_down(w, 8, 64));   // valid j<8
    float t  = __fadd_rn(u,  __shfl_down(u, 4, 64));   // valid j<4
    float r2 = __fadd_rn(t,  __shfl_down(t, 2, 64));   // valid j<2
    blk[bi]  = __fadd_rn(r2, __shfl_down(r2, 1, 64));  // valid j==0
  }
  return __fadd_rn(blk[0], blk[1]);                    // valid j==0
}

// frozen np distance, float4-load pipelined (IDENTICAL fma sequence/order)
__device__ __forceinline__ float np_dist_f4(const float* __restrict__ xp,
                                            const float* __restrict__ ep,
                                            float a, float b) {
  float m = 0.f;
  #pragma unroll 16
  for (int d4 = 0; d4 < DIMD / 4; ++d4) {
    const float4 xv = *(const float4*)(xp + d4 * 4);
    const float4 ev = *(const float4*)(ep + d4 * 4);
    m = fmaf(xv.x, ev.x, m);
    m = fmaf(xv.y, ev.y, m);
    m = fmaf(xv.z, ev.z, m);
    m = fmaf(xv.w, ev.w, m);
  }
  return __fadd_rn(__fsub_rn(a, __fmul_rn(2.0f, m)), b);
}

// fused prep: bf16 conversion of all codebooks + bK (frozen np sumsq) +
// zero lossP/done. 1024 blocks x 256 threads.
__global__ __launch_bounds__(256) void k_prep(const float* __restrict__ cb,
                                              unsigned short* __restrict__ cb16,
                                              float* __restrict__ bK,
                                              double* __restrict__ lossP,
                                              unsigned* __restrict__ done) {
  const int g = blockIdx.x * 256 + threadIdx.x;  // 0..262143
  {  // cb16: 4 elements per thread, exactly covers QQ*NE*DIMD
    const int i = g * 4;
    float4 f = *(const float4*)(cb + i);
    unsigned short t[4] = {f2bf(f.x), f2bf(f.y), f2bf(f.z), f2bf(f.w)};
    *(short4*)(cb16 + i) = *(short4*)t;
  }
  if (g < QQ * NE * 32) {  // bK: 32 lanes per row (frozen np tree)
    const int row = g >> 5, j = g & 31;
    float b = np_sumsq_256_x32(cb + (size_t)row * DIMD, j);
    if (j == 0) bK[row] = b;
  }
  if (g < QQ * 64) lossP[g] = 0.0;
  if (g == 0) *done = 0u;
}

// 512 threads = 8 waves; block owns TM=32 rows through ALL 4 stages.
// Wave w covers codes [w*128,(w+1)*128) as 8 col-tiles x 2 row-tiles (M_rep=2).
__global__ __launch_bounds__(512, 4) void k_fused(
    const float* __restrict__ x,              // [MM][DIMD]
    const unsigned short* __restrict__ cb16a, // [QQ][NE][DIMD] bf16
    const float* __restrict__ cba,            // [QQ][NE][DIMD] fp32
    const float* __restrict__ bKa,            // [QQ][NE]
    double* __restrict__ lossP,               // [QQ][64]
    unsigned* __restrict__ doneCnt,           // grid done counter
    float* __restrict__ out_q,                // [MM][DIMD]
    float* __restrict__ idx_out,              // [QQ][MM] floats
    float* __restrict__ out_loss) {           // [QQ]
  __shared__ float residF[TM][DIMD + 4];       // fp32 residual, all 4 stages
  __shared__ unsigned short sX[TM][DIMD + 8];  // bf16 rows
  __shared__ float  sBK[NE];                   // bK staged per stage
  __shared__ float  av_s[TM];
  __shared__ float  candD[TM][NW];
  __shared__ float  thrS[TM];
  __shared__ int    cnt[TM];
  __shared__ int    candL[TM][CAP];
  __shared__ float  candDist[TM][CAP];         // fp32 d~ of gathered cands
  __shared__ float  dcD[TM][CAP];
  __shared__ int    bcode[TM];
  __shared__ float  fwD[NW];
  __shared__ int    fwI[NW];
  __shared__ double lossW[NW];

  const int tid  = threadIdx.x;
  const int lane = tid & 63;
  const int wv   = tid >> 6;
  const int rowBase = blockIdx.x * TM;
  const int r16 = tid >> 4;        // row 0..31 (16 threads per row)
  const int j16 = tid & 15;        // lane in row-group
  const int d0  = j16 * 16;        // 16 floats per thread per row
  const int m16  = lane & 15;
  const int quad = lane >> 4;

  // x -> residF (exact fp32; stage-0 residual == x)
  {
    const float* xp = x + (size_t)(rowBase + r16) * DIMD + d0;
    #pragma unroll
    for (int h = 0; h < 4; ++h)
      *(float4*)&residF[r16][d0 + h * 4] = *(const float4*)(xp + h * 4);
  }
  __syncthreads();

  #pragma unroll 1
  for (int qi = 0; qi < QQ; ++qi) {
    const unsigned short* cb16 = cb16a + (size_t)qi * NE * DIMD;
    const float* cb = cba + (size_t)qi * NE * DIMD;
    const float* bK = bKa + (size_t)qi * NE;

    // av (FROZEN, 16-lane tree, from LDS) + cnt reset + bK->LDS + bf16 staging
    {
      float av = np_sumsq_256_x16(&residF[r16][0], j16);
      if (j16 == 0) av_s[r16] = av;
    }
    if (tid < TM) cnt[tid] = 0;
    sBK[tid] = bK[tid];
    sBK[tid + 512] = bK[tid + 512];
    {
      #pragma unroll
      for (int h = 0; h < 2; ++h) {
        const float* rp = &residF[r16][d0 + h * 8];
        const float4 f0 = *(const float4*)rp;
        const float4 f1 = *(const float4*)(rp + 4);
        unsigned short t[8] = {f2bf(f0.x), f2bf(f0.y), f2bf(f0.z), f2bf(f0.w),
                               f2bf(f1.x), f2bf(f1.y), f2bf(f1.z), f2bf(f1.w)};
        *(v8s*)&sX[r16][d0 + h * 8] = *(v8s*)t;
      }
    }
    __syncthreads();

    // per-wave bmax over sBK (fp32 fmax == old atomicMax value bit-exactly;
    // bK > 0 always). 16 LDS reads + shfl reduce per wave.
    float bmx;
    {
      float bm = sBK[lane];
      #pragma unroll
      for (int t = 1; t < 16; ++t) bm = fmaxf(bm, sBK[lane + t * 64]);
      #pragma unroll
      for (int off = 32; off; off >>= 1) bm = fmaxf(bm, __shfl_xor(bm, off, 64));
      bmx = bm;
    }

    // MFMA: M~[row][code], 2 row-tiles x 8 col-tiles per wave; per kc all 8
    // B-fragments batched (8 dwordx4 in flight), 16 MFMAs.
    v4f acc[2][8];
    #pragma unroll
    for (int mt = 0; mt < 2; ++mt)
      #pragma unroll
      for (int ct = 0; ct < 8; ++ct) acc[mt][ct] = (v4f)(0.f);
    const unsigned short* bptr =
        cb16 + ((size_t)(wv * 128 + m16)) * DIMD + quad * 8;
    #pragma unroll
    for (int kc = 0; kc < 8; ++kc) {
      v8s bfr[8];
      #pragma unroll
      for (int ct = 0; ct < 8; ++ct)
        bfr[ct] = *(const v8s*)(bptr + (size_t)ct * 16 * DIMD + kc * 32);
      v8s a0 = *(const v8s*)&sX[m16][kc * 32 + quad * 8];
      v8s a1 = *(const v8s*)&sX[16 + m16][kc * 32 + quad * 8];
      #pragma unroll
      for (int ct = 0; ct < 8; ++ct) {
        acc[0][ct] = __builtin_amdgcn_mfma_f32_16x16x32_bf16(a0, bfr[ct], acc[0][ct], 0, 0, 0);
        acc[1][ct] = __builtin_amdgcn_mfma_f32_16x16x32_bf16(a1, bfr[ct], acc[1][ct], 0, 0, 0);
      }
    }

    // approx dist in-place: d~ = a - 2*M~ + b  (D: row=mt*16+quad*4+v, col=m16)
    float av8[2][4];
    #pragma unroll
    for (int mt = 0; mt < 2; ++mt)
      #pragma unroll
      for (int v = 0; v < 4; ++v) av8[mt][v] = av_s[mt * 16 + quad * 4 + v];
    #pragma unroll
    for (int ct = 0; ct < 8; ++ct) {
      const float bv = sBK[wv * 128 + ct * 16 + m16];
      #pragma unroll
      for (int mt = 0; mt < 2; ++mt)
        #pragma unroll
        for (int v = 0; v < 4; ++v)
          acc[mt][ct][v] = av8[mt][v] - 2.0f * acc[mt][ct][v] + bv;
    }

    // per-row wave-local min over this wave's 128 codes
    float vmi[2][4];
    #pragma unroll
    for (int mt = 0; mt < 2; ++mt) {
      #pragma unroll
      for (int v = 0; v < 4; ++v) {
        float vm = acc[mt][0][v];
        #pragma unroll
        for (int ct = 1; ct < 8; ++ct) vm = fminf(vm, acc[mt][ct][v]);
        #pragma unroll
        for (int off = 1; off < 16; off <<= 1)
          vm = fminf(vm, __shfl_xor(vm, off, 64));
        vmi[mt][v] = vm;
      }
      if (m16 == 0) {
        #pragma unroll
        for (int v = 0; v < 4; ++v) candD[mt * 16 + quad * 4 + v][wv] = vmi[mt][v];
      }
    }

    // PRE-barrier gather with per-wave conservative threshold
    // thr_w = wave_min + tau >= thrS  -> certified SUPERSET; d~ stored fp32.
    // acc dies here: nothing lives across the barrier.
    float thrw[2][4];
    #pragma unroll
    for (int mt = 0; mt < 2; ++mt)
      #pragma unroll
      for (int v = 0; v < 4; ++v)
        thrw[mt][v] = vmi[mt][v] + 0.03125f * sqrtf(av8[mt][v] * bmx) + 0.1f;
    #pragma unroll
    for (int ct = 0; ct < 8; ++ct) {
      const int code = wv * 128 + ct * 16 + m16;
      #pragma unroll
      for (int mt = 0; mt < 2; ++mt) {
        #pragma unroll
        for (int v = 0; v < 4; ++v) {
          if (acc[mt][ct][v] <= thrw[mt][v]) {
            const int row = mt * 16 + quad * 4 + v;
            int pos = atomicAdd(&cnt[row], 1);
            if (pos < CAP) {
              candL[row][pos] = code;
              candDist[row][pos] = acc[mt][ct][v];
            }
          }
        }
      }
    }
    __syncthreads();

    // true threshold: bd = global min over wave minima; tau unchanged
    if (tid < TM) {
      float bd = candD[tid][0];
      #pragma unroll
      for (int w = 1; w < NW; ++w) bd = fminf(bd, candD[tid][w]);
      // certified margin: 2*2^-8*sqrt(a*bmax) needed; 2^-5*sqrt(.)+0.1 = 8x slack
      thrS[tid] = bd + 0.03125f * sqrtf(av_s[tid] * bmx) + 0.1f;
    }
    __syncthreads();

    // exact (frozen) distance per candidate with PRUNE: np_dist only where
    // d~ <= thrS (identical predicate & fp32 values as R14's gather -> the
    // np_dist set is bit-identical). thread (row, j16) covers slots j16, j16+16.
    {
      const int n = (cnt[r16] <= CAP) ? cnt[r16] : 0;  // overflow -> fallback
      if (j16 < n) {
        dcD[r16][j16] = (candDist[r16][j16] <= thrS[r16])
            ? np_dist_f4(&residF[r16][0],
                         cb + (size_t)candL[r16][j16] * DIMD,
                         av_s[r16], sBK[candL[r16][j16]])
            : 3.4e38f;
      }
      if (j16 + 16 < n) {
        dcD[r16][j16 + 16] = (candDist[r16][j16 + 16] <= thrS[r16])
            ? np_dist_f4(&residF[r16][0],
                         cb + (size_t)candL[r16][j16 + 16] * DIMD,
                         av_s[r16], sBK[candL[r16][j16 + 16]])
            : 3.4e38f;
      }
    }
    __syncthreads();

    // cooperative fallback for overflow rows (rare): 2 codes/thread, exact
    for (int r = 0; r < TM; ++r) {
      if (cnt[r] > CAP) {
        const float* xp = &residF[r][0];
        const float a = av_s[r];
        float d1 = np_dist_f4(xp, cb + (size_t)tid * DIMD, a, sBK[tid]);
        float d2 = np_dist_f4(xp, cb + (size_t)(tid + 512) * DIMD, a, sBK[tid + 512]);
        int i1 = tid;
        if (d2 < d1) { d1 = d2; i1 = tid + 512; }  // strict <: lower idx on tie
        #pragma unroll
        for (int off = 32; off; off >>= 1) {
          float vd = __shfl_xor(d1, off, 64);
          int vi = __shfl_xor(i1, off, 64);
          if (vd < d1 || (vd == d1 && vi < i1)) { d1 = vd; i1 = vi; }
        }
        if (lane == 0) { fwD[wv] = d1; fwI[wv] = i1; }
        __syncthreads();
        if (tid == 0) {
          float bd = fwD[0];
          int bi = fwI[0];
          #pragma unroll
          for (int w = 1; w < NW; ++w) {
            if (fwD[w] < bd || (fwD[w] == bd && fwI[w] < bi)) {
              bd = fwD[w]; bi = fwI[w];
            }
          }
          bcode[r] = bi;
        }
        __syncthreads();
      }
    }

    if (tid < TM) {
      if (cnt[tid] <= CAP) {
        float bd = 3.4e38f;
        int bi = 0x7fffffff;
        for (int ci = 0; ci < cnt[tid]; ++ci) {
          float d = dcD[tid][ci];
          int code = candL[tid][ci];
          if (d < bd || (d == bd && code < bi)) { bd = d; bi = code; }
        }
        bcode[tid] = bi;
      }
      idx_out[(size_t)qi * MM + rowBase + tid] = (float)bcode[tid];
    }
    __syncthreads();

    // STE update — FROZEN: t=fl(q-r); u=fl(r+t); r'=fl(r-u)  (in-LDS)
    const int codeB = bcode[r16];
    double lsum = 0.0;
    #pragma unroll
    for (int h = 0; h < 4; ++h) {
      const int d = d0 + h * 4;
      const float4 ev = *(const float4*)(cb + (size_t)codeB * DIMD + d);
      const float4 rv = *(const float4*)&residF[r16][d];
      float t0 = __fsub_rn(ev.x, rv.x), u0 = __fadd_rn(rv.x, t0);
      float t1 = __fsub_rn(ev.y, rv.y), u1 = __fadd_rn(rv.y, t1);
      float t2 = __fsub_rn(ev.z, rv.z), u2 = __fadd_rn(rv.z, t2);
      float t3 = __fsub_rn(ev.w, rv.w), u3 = __fadd_rn(rv.w, t3);
      *(float4*)&residF[r16][d] =
          make_float4(__fsub_rn(rv.x, u0), __fsub_rn(rv.y, u1),
                      __fsub_rn(rv.z, u2), __fsub_rn(rv.w, u3));
      lsum += (double)__fmul_rn(t0, t0) + (double)__fmul_rn(t1, t1) +
              (double)__fmul_rn(t2, t2) + (double)__fmul_rn(t3, t3);
    }
    #pragma unroll
    for (int off = 32; off; off >>= 1) lsum += __shfl_xor(lsum, off, 64);
    if (lane == 0) lossW[wv] = lsum;
    __syncthreads();   // also orders residF writes before next stage's reads
    if (tid == 0) {
      double s = 0.0;
      #pragma unroll
      for (int w = 0; w < NW; ++w) s += lossW[w];
      atomicAdd(lossP + (size_t)qi * 64 + (blockIdx.x & 63), s);
    }
  }

  // epilogue: out_q = fl(x - resid_final)
  {
    const float* xp = x + (size_t)(rowBase + r16) * DIMD + d0;
    float* op = out_q + (size_t)(rowBase + r16) * DIMD + d0;
    #pragma unroll
    for (int h = 0; h < 4; ++h) {
      const float4 a = *(const float4*)(xp + h * 4);
      const float4 b = *(const float4*)&residF[r16][d0 + h * 4];
      *(float4*)(op + h * 4) =
          make_float4(__fsub_rn(a.x, b.x), __fsub_rn(a.y, b.y),
                      __fsub_rn(a.z, b.z), __fsub_rn(a.w, b.w));
    }
  }

  // folded k_loss: last block to finish sums lossP (device-scope atomics
  // both sides; __threadfence orders this block's lossP adds before the
  // done increment).
  __syncthreads();
  if (tid == 0) {
    __threadfence();
    unsigned old = atomicAdd(doneCnt, 1u);
    cnt[0] = (old == (unsigned)(gridDim.x - 1)) ? 1 : 0;
  }
  __syncthreads();
  if (cnt[0] && tid < 64) {
    const int qi2 = tid >> 4;
    double s = 0.0;
    #pragma unroll
    for (int i = 0; i < 4; ++i)
      s += atomicAdd(lossP + (size_t)qi2 * 64 + (tid & 15) * 4 + i, 0.0);
    #pragma unroll
    for (int off = 8; off; off >>= 1) s += __shfl_down(s, off, 16);
    if ((tid & 15) == 0)
      out_loss[qi2] = (float)(s * (1.0 / (double)((size_t)MM * DIMD)));
  }
}

extern "C" void kernel_launch(void* const* d_in, const int* in_sizes, int n_in,
                              void* d_out, int out_size, void* d_ws, size_t ws_size,
                              hipStream_t stream) {
  const float* x = (const float*)d_in[0];        // [8,2048,256]
  const float* cb = (const float*)d_in[1];       // [4,1024,256]
  float* ws = (float*)d_ws;
  unsigned short* cb16 = (unsigned short*)ws;    // 1,048,576 ushort
  float* bK = ws + 524288;
  double* lossP = (double*)(ws + 528384);        // [QQ][64], byte off %8==0
  unsigned* done = (unsigned*)(ws + 528896);

  float* out = (float*)d_out;
  float* out_idx = out + (size_t)MM * DIMD;      // 4,194,304
  float* out_loss = out_idx + (size_t)QQ * MM;   // +65,536

  k_prep<<<dim3(1024), dim3(256), 0, stream>>>(cb, cb16, bK, lossP, done);
  k_fused<<<dim3(MM / TM), dim3(512), 0, stream>>>(x, cb16, cb, bK, lossP,
                                                   done, out, out_idx, out_loss);
}

// Round 6
// 323.343 us; speedup vs baseline: 1.5363x; 1.5363x over previous
//
#include <hip/hip_runtime.h>

// ResidualVQ: Q=4, N_EMBED=1024, DIM=256, B=8, S=2048 (fp32).
// out = [quantized 8*2048*256][indices-as-float 4*8*2048][losses 4]
//
// R18: R14 structure (the 283us best: TM=32, post-barrier gather, bfr[8]
// batch, unroll-16 np_dist) with the register BUDGET raised instead of the
// code contorted: launch_bounds(512,2) = 256 regs/wave. Six rounds of A/B
// showed TM=32's B-reuse beats TM=16 despite spill, and no restructuring at
// the 128-reg budget (R15 load-width, R17 pre-barrier gather) removed the
// spill; R17's superset gather additionally blew past CAP and triggered the
// serial fallback (447us). So: zero-spill by budget, accept 1 block/CU.
// Carried from R17 (benign, independent): k_prep consolidation, per-wave
// bmx from sBK (== old atomicMax bit-exactly), folded loss tail.
// Certified exact re-rank structure FROZEN (R11-R17): bf16-MFMA prefilter,
// tau margin 8x slack, frozen np fp32 distance chain, tie -> lower index,
// frozen STE recursion. Outputs bit-identical to R14.
#define QQ   4
#define NE   1024
#define DIMD 256
#define MM   16384
#define TM   32
#define NW   8      // waves per block (512 threads)
#define CAP  32     // candidate slots per row

typedef short v8s __attribute__((ext_vector_type(8)));   // 8 x bf16
typedef float v4f __attribute__((ext_vector_type(4)));

// ws layout (float offsets):
//  cb16  [QQ][NE][DIMD] ushort @ 0        (524,288 floats)
//  bK    [QQ][NE]              @ 524,288  (4,096)
//  lossP double[QQ][64]        @ 528,384  (byte 2,113,536 %8==0; 512 floats)
//  done  uint                  @ 528,896

__device__ __forceinline__ unsigned short f2bf(float f) {  // RNE fp32->bf16
  unsigned u = __float_as_uint(f);
  return (unsigned short)((u + 0x7FFFu + ((u >> 16) & 1u)) >> 16);
}

// FROZEN numpy pairwise sumsq of 256 f32, over a 32-aligned group of 32 lanes
// (j = lane-in-group). Valid on j==0. Identical op tree/pairing as scalar.
__device__ __forceinline__ float np_sumsq_256_x32(const float* __restrict__ p,
                                                  int j) {
  const int bi = j >> 4, L = j & 15;
  const float* q = p + bi * 128 + L;
  float s0 = __fmul_rn(q[0], q[0]);
  float s1 = __fmul_rn(q[16], q[16]);
  float s2 = __fmul_rn(q[32], q[32]);
  float s3 = __fmul_rn(q[48], q[48]);
  float s4 = __fmul_rn(q[64], q[64]);
  float s5 = __fmul_rn(q[80], q[80]);
  float s6 = __fmul_rn(q[96], q[96]);
  float s7 = __fmul_rn(q[112], q[112]);
  float w = __fadd_rn(__fadd_rn(__fadd_rn(s0, s1), __fadd_rn(s2, s3)),
                      __fadd_rn(__fadd_rn(s4, s5), __fadd_rn(s6, s7)));
  float u  = __fadd_rn(w,  __shfl_down(w, 8, 64));   // valid L<8
  float t  = __fadd_rn(u,  __shfl_down(u, 4, 64));   // valid L<4
  float r2 = __fadd_rn(t,  __shfl_down(t, 2, 64));   // valid L<2
  float bb = __fadd_rn(r2, __shfl_down(r2, 1, 64));  // valid L==0 -> blk[bi]
  return __fadd_rn(bb, __shfl_down(bb, 16, 64));     // valid j==0
}

// Same frozen tree over 16 lanes (j=0..15 in a 16-aligned group); bi serial.
// Operand pairing of every __fadd_rn identical to the scalar chain -> bit-exact.
__device__ __forceinline__ float np_sumsq_256_x16(const float* __restrict__ p,
                                                  int j) {
  float blk[2];
  #pragma unroll
  for (int bi = 0; bi < 2; ++bi) {
    const float* q = p + bi * 128 + j;
    float s0 = __fmul_rn(q[0], q[0]);
    float s1 = __fmul_rn(q[16], q[16]);
    float s2 = __fmul_rn(q[32], q[32]);
    float s3 = __fmul_rn(q[48], q[48]);
    float s4 = __fmul_rn(q[64], q[64]);
    float s5 = __fmul_rn(q[80], q[80]);
    float s6 = __fmul_rn(q[96], q[96]);
    float s7 = __fmul_rn(q[112], q[112]);
    float w = __fadd_rn(__fadd_rn(__fadd_rn(s0, s1), __fadd_rn(s2, s3)),
                        __fadd_rn(__fadd_rn(s4, s5), __fadd_rn(s6, s7)));
    float u  = __fadd_rn(w,  __shfl_down(w, 8, 64));   // valid j<8
    float t  = __fadd_rn(u,  __shfl_down(u, 4, 64));   // valid j<4
    float r2 = __fadd_rn(t,  __shfl_down(t, 2, 64));   // valid j<2
    blk[bi]  = __fadd_rn(r2, __shfl_down(r2, 1, 64));  // valid j==0
  }
  return __fadd_rn(blk[0], blk[1]);                    // valid j==0
}

// frozen np distance, float4-load pipelined (IDENTICAL fma sequence/order)
__device__ __forceinline__ float np_dist_f4(const float* __restrict__ xp,
                                            const float* __restrict__ ep,
                                            float a, float b) {
  float m = 0.f;
  #pragma unroll 16
  for (int d4 = 0; d4 < DIMD / 4; ++d4) {
    const float4 xv = *(const float4*)(xp + d4 * 4);
    const float4 ev = *(const float4*)(ep + d4 * 4);
    m = fmaf(xv.x, ev.x, m);
    m = fmaf(xv.y, ev.y, m);
    m = fmaf(xv.z, ev.z, m);
    m = fmaf(xv.w, ev.w, m);
  }
  return __fadd_rn(__fsub_rn(a, __fmul_rn(2.0f, m)), b);
}

// fused prep: bf16 conversion of all codebooks + bK (frozen np sumsq) +
// zero lossP/done. 1024 blocks x 256 threads.
__global__ __launch_bounds__(256) void k_prep(const float* __restrict__ cb,
                                              unsigned short* __restrict__ cb16,
                                              float* __restrict__ bK,
                                              double* __restrict__ lossP,
                                              unsigned* __restrict__ done) {
  const int g = blockIdx.x * 256 + threadIdx.x;  // 0..262143
  {  // cb16: 4 elements per thread, exactly covers QQ*NE*DIMD
    const int i = g * 4;
    float4 f = *(const float4*)(cb + i);
    unsigned short t[4] = {f2bf(f.x), f2bf(f.y), f2bf(f.z), f2bf(f.w)};
    *(short4*)(cb16 + i) = *(short4*)t;
  }
  if (g < QQ * NE * 32) {  // bK: 32 lanes per row (frozen np tree)
    const int row = g >> 5, j = g & 31;
    float b = np_sumsq_256_x32(cb + (size_t)row * DIMD, j);
    if (j == 0) bK[row] = b;
  }
  if (g < QQ * 64) lossP[g] = 0.0;
  if (g == 0) *done = 0u;
}

// 512 threads = 8 waves; block owns TM=32 rows through ALL 4 stages.
// Wave w covers codes [w*128,(w+1)*128) as 8 col-tiles x 2 row-tiles (M_rep=2).
// launch_bounds(512,2): 256 regs/wave -> acc[2][8]+bfr[8] fit, zero spill.
__global__ __launch_bounds__(512, 2) void k_fused(
    const float* __restrict__ x,              // [MM][DIMD]
    const unsigned short* __restrict__ cb16a, // [QQ][NE][DIMD] bf16
    const float* __restrict__ cba,            // [QQ][NE][DIMD] fp32
    const float* __restrict__ bKa,            // [QQ][NE]
    double* __restrict__ lossP,               // [QQ][64]
    unsigned* __restrict__ doneCnt,           // grid done counter
    float* __restrict__ out_q,                // [MM][DIMD]
    float* __restrict__ idx_out,              // [QQ][MM] floats
    float* __restrict__ out_loss) {           // [QQ]
  __shared__ float residF[TM][DIMD + 4];       // fp32 residual, all 4 stages
  __shared__ unsigned short sX[TM][DIMD + 8];  // bf16 rows
  __shared__ float  sBK[NE];                   // bK staged per stage
  __shared__ float  av_s[TM];
  __shared__ float  candD[TM][NW];
  __shared__ float  thrS[TM];
  __shared__ int    cnt[TM];
  __shared__ int    candL[TM][CAP];
  __shared__ float  dcD[TM][CAP];
  __shared__ int    bcode[TM];
  __shared__ float  fwD[NW];
  __shared__ int    fwI[NW];
  __shared__ double lossW[NW];

  const int tid  = threadIdx.x;
  const int lane = tid & 63;
  const int wv   = tid >> 6;
  const int rowBase = blockIdx.x * TM;
  const int r16 = tid >> 4;        // row 0..31 (16 threads per row)
  const int j16 = tid & 15;        // lane in row-group
  const int d0  = j16 * 16;        // 16 floats per thread per row
  const int m16  = lane & 15;
  const int quad = lane >> 4;

  // x -> residF (exact fp32; stage-0 residual == x)
  {
    const float* xp = x + (size_t)(rowBase + r16) * DIMD + d0;
    #pragma unroll
    for (int h = 0; h < 4; ++h)
      *(float4*)&residF[r16][d0 + h * 4] = *(const float4*)(xp + h * 4);
  }
  __syncthreads();

  #pragma unroll 1
  for (int qi = 0; qi < QQ; ++qi) {
    const unsigned short* cb16 = cb16a + (size_t)qi * NE * DIMD;
    const float* cb = cba + (size_t)qi * NE * DIMD;
    const float* bK = bKa + (size_t)qi * NE;

    // av (FROZEN, 16-lane tree, from LDS) + cnt reset + bK->LDS + bf16 staging
    {
      float av = np_sumsq_256_x16(&residF[r16][0], j16);
      if (j16 == 0) av_s[r16] = av;
    }
    if (tid < TM) cnt[tid] = 0;
    sBK[tid] = bK[tid];
    sBK[tid + 512] = bK[tid + 512];
    {
      #pragma unroll
      for (int h = 0; h < 2; ++h) {
        const float* rp = &residF[r16][d0 + h * 8];
        const float4 f0 = *(const float4*)rp;
        const float4 f1 = *(const float4*)(rp + 4);
        unsigned short t[8] = {f2bf(f0.x), f2bf(f0.y), f2bf(f0.z), f2bf(f0.w),
                               f2bf(f1.x), f2bf(f1.y), f2bf(f1.z), f2bf(f1.w)};
        *(v8s*)&sX[r16][d0 + h * 8] = *(v8s*)t;
      }
    }
    __syncthreads();

    // per-wave bmax over sBK (fp32 fmax == old atomicMax value bit-exactly;
    // bK > 0 always). 16 LDS reads + shfl reduce per wave.
    float bmx;
    {
      float bm = sBK[lane];
      #pragma unroll
      for (int t = 1; t < 16; ++t) bm = fmaxf(bm, sBK[lane + t * 64]);
      #pragma unroll
      for (int off = 32; off; off >>= 1) bm = fmaxf(bm, __shfl_xor(bm, off, 64));
      bmx = bm;
    }

    // MFMA: M~[row][code], 2 row-tiles x 8 col-tiles per wave; per kc all 8
    // B-fragments batched (8 dwordx4 in flight), 16 MFMAs.
    v4f acc[2][8];
    #pragma unroll
    for (int mt = 0; mt < 2; ++mt)
      #pragma unroll
      for (int ct = 0; ct < 8; ++ct) acc[mt][ct] = (v4f)(0.f);
    const unsigned short* bptr =
        cb16 + ((size_t)(wv * 128 + m16)) * DIMD + quad * 8;
    #pragma unroll
    for (int kc = 0; kc < 8; ++kc) {
      v8s bfr[8];
      #pragma unroll
      for (int ct = 0; ct < 8; ++ct)
        bfr[ct] = *(const v8s*)(bptr + (size_t)ct * 16 * DIMD + kc * 32);
      v8s a0 = *(const v8s*)&sX[m16][kc * 32 + quad * 8];
      v8s a1 = *(const v8s*)&sX[16 + m16][kc * 32 + quad * 8];
      #pragma unroll
      for (int ct = 0; ct < 8; ++ct) {
        acc[0][ct] = __builtin_amdgcn_mfma_f32_16x16x32_bf16(a0, bfr[ct], acc[0][ct], 0, 0, 0);
        acc[1][ct] = __builtin_amdgcn_mfma_f32_16x16x32_bf16(a1, bfr[ct], acc[1][ct], 0, 0, 0);
      }
    }

    // approx dist in-place: d~ = a - 2*M~ + b  (D: row=mt*16+quad*4+v, col=m16)
    float av8[2][4];
    #pragma unroll
    for (int mt = 0; mt < 2; ++mt)
      #pragma unroll
      for (int v = 0; v < 4; ++v) av8[mt][v] = av_s[mt * 16 + quad * 4 + v];
    #pragma unroll
    for (int ct = 0; ct < 8; ++ct) {
      const float bv = sBK[wv * 128 + ct * 16 + m16];
      #pragma unroll
      for (int mt = 0; mt < 2; ++mt)
        #pragma unroll
        for (int v = 0; v < 4; ++v)
          acc[mt][ct][v] = av8[mt][v] - 2.0f * acc[mt][ct][v] + bv;
    }

    // per-row min: over ct, then across the 16 lanes of each quad
    #pragma unroll
    for (int mt = 0; mt < 2; ++mt) {
      float vmin[4];
      #pragma unroll
      for (int v = 0; v < 4; ++v) {
        vmin[v] = acc[mt][0][v];
        #pragma unroll
        for (int ct = 1; ct < 8; ++ct) vmin[v] = fminf(vmin[v], acc[mt][ct][v]);
        #pragma unroll
        for (int off = 1; off < 16; off <<= 1)
          vmin[v] = fminf(vmin[v], __shfl_xor(vmin[v], off, 64));
      }
      if (m16 == 0) {
        #pragma unroll
        for (int v = 0; v < 4; ++v) candD[mt * 16 + quad * 4 + v][wv] = vmin[v];
      }
    }
    __syncthreads();
    if (tid < TM) {
      float bd = candD[tid][0];
      #pragma unroll
      for (int w = 1; w < NW; ++w) bd = fminf(bd, candD[tid][w]);
      // certified margin: 2*2^-8*sqrt(a*bmax) needed; 2^-5*sqrt(.)+0.1 = 8x slack
      thrS[tid] = bd + 0.03125f * sqrtf(av_s[tid] * bmx) + 0.1f;
    }
    __syncthreads();

    // gather candidates (acc stays live across the barrier; 256-reg budget
    // holds it without spill)
    #pragma unroll
    for (int ct = 0; ct < 8; ++ct) {
      const int code = wv * 128 + ct * 16 + m16;
      #pragma unroll
      for (int mt = 0; mt < 2; ++mt) {
        #pragma unroll
        for (int v = 0; v < 4; ++v) {
          const int row = mt * 16 + quad * 4 + v;
          if (acc[mt][ct][v] <= thrS[row]) {
            int pos = atomicAdd(&cnt[row], 1);
            if (pos < CAP) candL[row][pos] = code;
          }
        }
      }
    }
    __syncthreads();

    // exact (frozen) distance per candidate: thread (row, j16) covers slots
    // j16 and j16+16 (x from LDS: identical fp32 values, identical fma order)
    {
      const int n = (cnt[r16] <= CAP) ? cnt[r16] : 0;  // overflow -> fallback
      if (j16 < n) {
        const int code = candL[r16][j16];
        dcD[r16][j16] = np_dist_f4(&residF[r16][0], cb + (size_t)code * DIMD,
                                   av_s[r16], sBK[code]);
      }
      if (j16 + 16 < n) {
        const int code = candL[r16][j16 + 16];
        dcD[r16][j16 + 16] = np_dist_f4(&residF[r16][0], cb + (size_t)code * DIMD,
                                        av_s[r16], sBK[code]);
      }
    }
    __syncthreads();

    // cooperative fallback for overflow rows (rare): 2 codes/thread, exact
    for (int r = 0; r < TM; ++r) {
      if (cnt[r] > CAP) {
        const float* xp = &residF[r][0];
        const float a = av_s[r];
        float d1 = np_dist_f4(xp, cb + (size_t)tid * DIMD, a, sBK[tid]);
        float d2 = np_dist_f4(xp, cb + (size_t)(tid + 512) * DIMD, a, sBK[tid + 512]);
        int i1 = tid;
        if (d2 < d1) { d1 = d2; i1 = tid + 512; }  // strict <: lower idx on tie
        #pragma unroll
        for (int off = 32; off; off >>= 1) {
          float vd = __shfl_xor(d1, off, 64);
          int vi = __shfl_xor(i1, off, 64);
          if (vd < d1 || (vd == d1 && vi < i1)) { d1 = vd; i1 = vi; }
        }
        if (lane == 0) { fwD[wv] = d1; fwI[wv] = i1; }
        __syncthreads();
        if (tid == 0) {
          float bd = fwD[0];
          int bi = fwI[0];
          #pragma unroll
          for (int w = 1; w < NW; ++w) {
            if (fwD[w] < bd || (fwD[w] == bd && fwI[w] < bi)) {
              bd = fwD[w]; bi = fwI[w];
            }
          }
          bcode[r] = bi;
        }
        __syncthreads();
      }
    }

    if (tid < TM) {
      if (cnt[tid] <= CAP) {
        float bd = 3.4e38f;
        int bi = 0x7fffffff;
        for (int ci = 0; ci < cnt[tid]; ++ci) {
          float d = dcD[tid][ci];
          int code = candL[tid][ci];
          if (d < bd || (d == bd && code < bi)) { bd = d; bi = code; }
        }
        bcode[tid] = bi;
      }
      idx_out[(size_t)qi * MM + rowBase + tid] = (float)bcode[tid];
    }
    __syncthreads();

    // STE update — FROZEN: t=fl(q-r); u=fl(r+t); r'=fl(r-u)  (in-LDS)
    const int codeB = bcode[r16];
    double lsum = 0.0;
    #pragma unroll
    for (int h = 0; h < 4; ++h) {
      const int d = d0 + h * 4;
      const float4 ev = *(const float4*)(cb + (size_t)codeB * DIMD + d);
      const float4 rv = *(const float4*)&residF[r16][d];
      float t0 = __fsub_rn(ev.x, rv.x), u0 = __fadd_rn(rv.x, t0);
      float t1 = __fsub_rn(ev.y, rv.y), u1 = __fadd_rn(rv.y, t1);
      float t2 = __fsub_rn(ev.z, rv.z), u2 = __fadd_rn(rv.z, t2);
      float t3 = __fsub_rn(ev.w, rv.w), u3 = __fadd_rn(rv.w, t3);
      *(float4*)&residF[r16][d] =
          make_float4(__fsub_rn(rv.x, u0), __fsub_rn(rv.y, u1),
                      __fsub_rn(rv.z, u2), __fsub_rn(rv.w, u3));
      lsum += (double)__fmul_rn(t0, t0) + (double)__fmul_rn(t1, t1) +
              (double)__fmul_rn(t2, t2) + (double)__fmul_rn(t3, t3);
    }
    #pragma unroll
    for (int off = 32; off; off >>= 1) lsum += __shfl_xor(lsum, off, 64);
    if (lane == 0) lossW[wv] = lsum;
    __syncthreads();   // also orders residF writes before next stage's reads
    if (tid == 0) {
      double s = 0.0;
      #pragma unroll
      for (int w = 0; w < NW; ++w) s += lossW[w];
      atomicAdd(lossP + (size_t)qi * 64 + (blockIdx.x & 63), s);
    }
  }

  // epilogue: out_q = fl(x - resid_final)
  {
    const float* xp = x + (size_t)(rowBase + r16) * DIMD + d0;
    float* op = out_q + (size_t)(rowBase + r16) * DIMD + d0;
    #pragma unroll
    for (int h = 0; h < 4; ++h) {
      const float4 a = *(const float4*)(xp + h * 4);
      const float4 b = *(const float4*)&residF[r16][d0 + h * 4];
      *(float4*)(op + h * 4) =
          make_float4(__fsub_rn(a.x, b.x), __fsub_rn(a.y, b.y),
                      __fsub_rn(a.z, b.z), __fsub_rn(a.w, b.w));
    }
  }

  // folded k_loss: last block to finish sums lossP (device-scope atomics
  // both sides; __threadfence orders this block's lossP adds before the
  // done increment).
  __syncthreads();
  if (tid == 0) {
    __threadfence();
    unsigned old = atomicAdd(doneCnt, 1u);
    cnt[0] = (old == (unsigned)(gridDim.x - 1)) ? 1 : 0;
  }
  __syncthreads();
  if (cnt[0] && tid < 64) {
    const int qi2 = tid >> 4;
    double s = 0.0;
    #pragma unroll
    for (int i = 0; i < 4; ++i)
      s += atomicAdd(lossP + (size_t)qi2 * 64 + (tid & 15) * 4 + i, 0.0);
    #pragma unroll
    for (int off = 8; off; off >>= 1) s += __shfl_down(s, off, 16);
    if ((tid & 15) == 0)
      out_loss[qi2] = (float)(s * (1.0 / (double)((size_t)MM * DIMD)));
  }
}

extern "C" void kernel_launch(void* const* d_in, const int* in_sizes, int n_in,
                              void* d_out, int out_size, void* d_ws, size_t ws_size,
                              hipStream_t stream) {
  const float* x = (const float*)d_in[0];        // [8,2048,256]
  const float* cb = (const float*)d_in[1];       // [4,1024,256]
  float* ws = (float*)d_ws;
  unsigned short* cb16 = (unsigned short*)ws;    // 1,048,576 ushort
  float* bK = ws + 524288;
  double* lossP = (double*)(ws + 528384);        // [QQ][64], byte off %8==0
  unsigned* done = (unsigned*)(ws + 528896);

  float* out = (float*)d_out;
  float* out_idx = out + (size_t)MM * DIMD;      // 4,194,304
  float* out_loss = out_idx + (size_t)QQ * MM;   // +65,536

  k_prep<<<dim3(1024), dim3(256), 0, stream>>>(cb, cb16, bK, lossP, done);
  k_fused<<<dim3(MM / TM), dim3(512), 0, stream>>>(x, cb16, cb, bK, lossP,
                                                   done, out, out_idx, out_loss);
}